// Round 14
// baseline (136.936 us; speedup 1.0000x reference)
//
#include <hip/hip_runtime.h>

#define HEADS 16
#define HD 64
#define SEQ 2048
#define DMODEL 1024
#define BATCH 2
#define MTOT (BATCH*SEQ)   // 4096
#define KVB 64
#define NKH 16             // k-tiles per half (split-k=2)

typedef unsigned short u16;
typedef __bf16 bf16;
typedef bf16 bf16x8 __attribute__((ext_vector_type(8)));
typedef float f32x4 __attribute__((ext_vector_type(4)));
typedef float f32x16 __attribute__((ext_vector_type(16)));
typedef unsigned short u16x8 __attribute__((ext_vector_type(8)));
typedef unsigned short u16x4 __attribute__((ext_vector_type(4)));

static __device__ __forceinline__ u16 f2bf(float f) {
  bf16 b = (bf16)f;
  return __builtin_bit_cast(u16, b);
}

// async global->LDS, 16B per lane. LDS dest is wave-uniform base; HW scatters
// lane i at base + 16*i. Global src is per-lane (enables source pre-swizzle).
static __device__ __forceinline__ void async16(u16* lds_base, const u16* g) {
  __builtin_amdgcn_global_load_lds(
      (const __attribute__((address_space(1))) unsigned int*)g,
      (__attribute__((address_space(3))) unsigned int*)lds_base,
      16, 0, 0);
}

// ---------------- convert x: f32 -> bf16, 8 elems/thread ----------------
__global__ __launch_bounds__(256) void k_cvt(const float* __restrict__ in,
                                             u16* __restrict__ out, int n8) {
  int i = blockIdx.x * blockDim.x + threadIdx.x;
  if (i >= n8) return;
  const float4* p = (const float4*)(in + (size_t)i * 8);
  float4 a = p[0], b = p[1];
  u16x8 r;
  r[0] = f2bf(a.x); r[1] = f2bf(a.y); r[2] = f2bf(a.z); r[3] = f2bf(a.w);
  r[4] = f2bf(b.x); r[5] = f2bf(b.y); r[6] = f2bf(b.z); r[7] = f2bf(b.w);
  *(u16x8*)(out + (size_t)i * 8) = r;
}

// ------------- convert + transpose W: f32 [K,N] -> bf16 [N,K] -------------
__global__ __launch_bounds__(256) void k_cvtT(const float* __restrict__ W0, const float* __restrict__ W1,
                                              const float* __restrict__ W2, const float* __restrict__ W3,
                                              u16* __restrict__ T0, u16* __restrict__ T1,
                                              u16* __restrict__ T2, u16* __restrict__ T3) {
  const float* W = blockIdx.z == 0 ? W0 : blockIdx.z == 1 ? W1 : blockIdx.z == 2 ? W2 : W3;
  u16*         T = blockIdx.z == 0 ? T0 : blockIdx.z == 1 ? T1 : blockIdx.z == 2 ? T2 : T3;
  __shared__ u16 tile[64 * 68];
  int t = threadIdx.x;
  int kb = blockIdx.y * 64, nb = blockIdx.x * 64;
#pragma unroll
  for (int i = 0; i < 4; ++i) {
    int c = t * 4 + i;
    int row = c >> 4;
    int c4 = c & 15;
    float4 v = *(const float4*)&W[(size_t)(kb + row) * DMODEL + nb + c4 * 4];
    tile[row * 68 + c4 * 4 + 0] = f2bf(v.x);
    tile[row * 68 + c4 * 4 + 1] = f2bf(v.y);
    tile[row * 68 + c4 * 4 + 2] = f2bf(v.z);
    tile[row * 68 + c4 * 4 + 3] = f2bf(v.w);
  }
  __syncthreads();
#pragma unroll
  for (int i = 0; i < 2; ++i) {
    int c = t * 2 + i;
    int n = c >> 3;
    int k8 = c & 7;
    u16x8 v;
#pragma unroll
    for (int e = 0; e < 8; ++e) v[e] = tile[(k8 * 8 + e) * 68 + n];
    *(u16x8*)&T[(size_t)(nb + n) * DMODEL + kb + k8 * 8] = v;
  }
}

// -------- GEMM: C[M,N] = A[M,K] @ BT[N,K]^T + bias --------
// 2-phase double-buffered pipeline: stage next K-tile via global_load_lds
// BEFORE computing the current one; one raw s_barrier + own-wave vmcnt(0)
// per K-step (no full-drain __syncthreads pair).
// MODE 0 (QKV): z=0 -> Q*(scale*log2e) head-split [bh][n][hd]
//               z=1 -> K head-split [bh][n][hd]
//               z=2 -> V^T [bh][hd][n'] with n' = per-16-group k-permutation
//                      (swap bits 2<->3 of n&15) matching the attn C/D-reg
//                      score order, so PV needs no cross-lane redistribution.
// MODE 1: out f32 [M,N].
template <int MODE>
__global__ __launch_bounds__(256) void k_gemm(
    const u16* __restrict__ A,
    const u16* __restrict__ BT0, const u16* __restrict__ BT1, const u16* __restrict__ BT2,
    const float* __restrict__ b0, const float* __restrict__ b1, const float* __restrict__ b2,
    void* __restrict__ O0, void* __restrict__ O1, void* __restrict__ O2,
    int M, int N, int K) {
  const u16* BT = blockIdx.z == 0 ? BT0 : blockIdx.z == 1 ? BT1 : BT2;
  const float* bias = blockIdx.z == 0 ? b0 : blockIdx.z == 1 ? b1 : b2;
  void* Out = blockIdx.z == 0 ? O0 : blockIdx.z == 1 ? O1 : O2;

  __shared__ u16 Ads[2][128 * 32];  // 16KB
  __shared__ u16 Bds[2][128 * 32];  // 16KB
  int tid = threadIdx.x, wid = tid >> 6, lane = tid & 63;
  int r = lane & 15, g = lane >> 4;
  int wm = wid >> 1, wn = wid & 1;
  int m0 = blockIdx.y * 128, n0 = blockIdx.x * 128;

  f32x4 acc[4][4];
  f32x4 zero4 = {0.f, 0.f, 0.f, 0.f};
#pragma unroll
  for (int mt = 0; mt < 4; ++mt)
#pragma unroll
    for (int nt = 0; nt < 4; ++nt) acc[mt][nt] = zero4;

  int srow = lane >> 2;
  int scb = lane & 3;

  auto STAGE = [&](int b, int k0) {
#pragma unroll
    for (int tt = 0; tt < 2; ++tt) {
      int inst = wid * 2 + tt;
      int row = inst * 16 + srow;
      async16(&Ads[b][inst * 512], &A[(size_t)(m0 + row) * K + k0 + scb * 8]);
      async16(&Bds[b][inst * 512], &BT[(size_t)(n0 + row) * K + k0 + scb * 8]);
    }
  };

  auto BODY = [&](int buf, int k0) {
    if (k0 + 32 < K) STAGE(buf ^ 1, k0 + 32);  // flies under this step's MFMA
    bf16x8 af[4], bfv[4];
#pragma unroll
    for (int mt = 0; mt < 4; ++mt)
      af[mt] = *(const bf16x8*)&Ads[buf][(wm * 64 + mt * 16 + r) * 32 + g * 8];
#pragma unroll
    for (int nt = 0; nt < 4; ++nt)
      bfv[nt] = *(const bf16x8*)&Bds[buf][(wn * 64 + nt * 16 + r) * 32 + g * 8];
#pragma unroll
    for (int mt = 0; mt < 4; ++mt)
#pragma unroll
      for (int nt = 0; nt < 4; ++nt)
        acc[mt][nt] = __builtin_amdgcn_mfma_f32_16x16x32_bf16(af[mt], bfv[nt], acc[mt][nt], 0, 0, 0);
    // own-wave stage done; ds_reads all consumed by MFMAs above
    asm volatile("s_waitcnt vmcnt(0)" ::: "memory");
    __builtin_amdgcn_sched_barrier(0);
    __builtin_amdgcn_s_barrier();
    __builtin_amdgcn_sched_barrier(0);
  };

  STAGE(0, 0);
  asm volatile("s_waitcnt vmcnt(0)" ::: "memory");
  __builtin_amdgcn_sched_barrier(0);
  __builtin_amdgcn_s_barrier();
  __builtin_amdgcn_sched_barrier(0);

  for (int k0 = 0; k0 < K; k0 += 64) {  // K % 64 == 0
    BODY(0, k0);
    BODY(1, k0 + 32);
  }

  const float qs = 0.18033688011112042f;  // hd^-0.5 * log2(e)
#pragma unroll
  for (int nt = 0; nt < 4; ++nt) {
    int col = n0 + wn * 64 + nt * 16 + r;
    float bv = bias[col];
#pragma unroll
    for (int mt = 0; mt < 4; ++mt) {
      int rowb = m0 + wm * 64 + mt * 16 + g * 4;
      if (MODE == 0) {
        int b = rowb >> 11;
        int h = col >> 6, d = col & (HD - 1);
        if (blockIdx.z == 2) {
          // V^T with per-16-group k-permutation (rowb is 4-aligned, so the
          // 4-elem store stays contiguous under the bit-2<->3 swap)
          int n = rowb & (SEQ - 1);
          int np = (n & ~12) | ((n & 4) << 1) | ((n & 8) >> 1);
          u16x4 pk;
#pragma unroll
          for (int j = 0; j < 4; ++j) pk[j] = f2bf(acc[mt][nt][j] + bv);
          *(u16x4*)&((u16*)Out)[((size_t)((b * HEADS + h) * HD + d)) * SEQ + np] = pk;
        } else {
          float sc = (blockIdx.z == 0) ? qs : 1.0f;
#pragma unroll
          for (int j = 0; j < 4; ++j) {
            int row = rowb + j;
            int n = row & (SEQ - 1);
            ((u16*)Out)[((size_t)(b * HEADS + h) * SEQ + n) * HD + d] = f2bf((acc[mt][nt][j] + bv) * sc);
          }
        }
      } else {
#pragma unroll
        for (int j = 0; j < 4; ++j)
          ((float*)Out)[(size_t)(rowb + j) * N + col] = acc[mt][nt][j] + bv;
      }
    }
  }
}

// -------- flash attention: LDS-free main loop, direct-global K/V --------
// K/V per head = 512KB; XCD swizzle keeps 4 heads (2MB) L2-resident, and each
// 16KB tile is L1-resident across its 2 consumer waves -> staging through LDS
// bought 4x reuse at the cost of a block-wide barrier + vmcnt drain per body
// (the unhidable stall of R10/R13). Here each wave reads K/V fragments
// directly from global (16x16B loads/tile, plain (2c+hi)*8 chunk offsets --
// the XOR swizzle existed only for LDS banks) and runs with NO mid-loop
// barriers: waves fully independent, 2 blocks/CU co-resident (LDS = 24KB
// combine buffer only). Irreducible VMEM->reg traffic 512MB ~= 13us at L1 BW.
// Block = 4 waves (256 thr): wave = (q-pair s=w&1 [64 rows, subtiles A/B],
// k-half h=w>>1 [1024 keys]). Swapped QK^T on 32x32x16 MFMA; softmax = exp2
// only (scores bounded, shift-invariance -> m==0 exact). Split-K combines by
// exact ADD through LDS at the end (only __syncthreads in the kernel).
__global__ __launch_bounds__(256, 2) void k_attn(const u16* __restrict__ Q,
                                                 const u16* __restrict__ Kg,
                                                 const u16* __restrict__ Vt,
                                                 u16* __restrict__ Oa) {
  __shared__ float cf[2 * 3072];  // 24KB split-K combine buffer

  int tid = threadIdx.x, wid = tid >> 6, lane = tid & 63;
  int l31 = lane & 31, hi = lane >> 5;
  int h = wid >> 1, s = wid & 1;

  // XCD-aware swizzle: 512 blocks, 8 XCDs -> 4 heads per XCD (K/V L2-resident)
  int fid = blockIdx.y * gridDim.x + blockIdx.x;  // gridDim = (16, 32)
  int swz = (fid & 7) * 64 + (fid >> 3);
  int qt = swz & 15;
  int bh = swz >> 4;

  const size_t kbase = (size_t)bh * SEQ * HD;  // Q,K: [bh][n][64]
  const size_t vbase = (size_t)bh * HD * SEQ;  // Vt:  [bh][64][2048'] (k-permuted)
  int qA = qt * 128 + s * 64;  // subtile A rows; B = +32

  // Q as the QK^T B-operand: col q = l31, contraction slot (hi,e) = d hi*8+e
  bf16x8 qfA[4], qfB[4];
#pragma unroll
  for (int db = 0; db < 4; ++db) {
    qfA[db] = *(const bf16x8*)&Q[kbase + (size_t)(qA + l31) * HD + db * 16 + hi * 8];
    qfB[db] = *(const bf16x8*)&Q[kbase + (size_t)(qA + 32 + l31) * HD + db * 16 + hi * 8];
  }

  f32x16 zero16 = {0.f,0.f,0.f,0.f,0.f,0.f,0.f,0.f,0.f,0.f,0.f,0.f,0.f,0.f,0.f,0.f};
  f32x16 oa0A = zero16, oa1A = zero16, lA = zero16;
  f32x16 oa0B = zero16, oa1B = zero16, lB = zero16;

  u16x8 onesb;
#pragma unroll
  for (int e = 0; e < 8; ++e) onesb[e] = 0x3F80;  // bf16 1.0
  bf16x8 ones = __builtin_bit_cast(bf16x8, onesb);

  for (int kc = 0; kc < NKH; ++kc) {
    int kof = (h * NKH + kc) * KVB;
    const u16* Kt = Kg + kbase + (size_t)kof * HD;  // K tile: [64][64]
    const u16* Vp = Vt + vbase + kof;               // V^T tile: [64 d][64 k']

    // ---- K fragments direct from global (L1/L2-served) ----
    bf16x8 kf0[4], kf1[4];
#pragma unroll
    for (int db = 0; db < 4; ++db) {
      kf0[db] = *(const bf16x8*)&Kt[(size_t)l31 * HD + (2 * db + hi) * 8];
      kf1[db] = *(const bf16x8*)&Kt[(size_t)(32 + l31) * HD + (2 * db + hi) * 8];
    }

    // ---- QK^T (swapped): each K fragment feeds BOTH q-subtiles ----
    f32x16 s0A = zero16, s1A = zero16, s0B = zero16, s1B = zero16;
#pragma unroll
    for (int db = 0; db < 4; ++db) {
      s0A = __builtin_amdgcn_mfma_f32_32x32x16_bf16(kf0[db], qfA[db], s0A, 0, 0, 0);
      s1A = __builtin_amdgcn_mfma_f32_32x32x16_bf16(kf1[db], qfA[db], s1A, 0, 0, 0);
      s0B = __builtin_amdgcn_mfma_f32_32x32x16_bf16(kf0[db], qfB[db], s0B, 0, 0, 0);
      s1B = __builtin_amdgcn_mfma_f32_32x32x16_bf16(kf1[db], qfB[db], s1B, 0, 0, 0);
    }
    // lane (l31,hi) holds S[q=l31][k = (reg&3) + 8*(reg>>2) + 4*hi (+32 for s1)]

    // ---- constant-shift softmax: P = exp2(S); V direct from global ----
    // pa slot (hi,e) = P[q][16t + (e&3) + 8*(e>>2) + 4*hi]; V^T chunk (2t+hi)
    // holds V[k] in exactly this order (pre-permuted at the GEMM epilogue).
#pragma unroll
    for (int t = 0; t < 4; ++t) {
      u16x8 pkA, pkB;
#pragma unroll
      for (int e = 0; e < 8; ++e) {
        float svA = (t & 2) ? ((t & 1) ? s1A[8 + e] : s1A[e])
                            : ((t & 1) ? s0A[8 + e] : s0A[e]);
        float svB = (t & 2) ? ((t & 1) ? s1B[8 + e] : s1B[e])
                            : ((t & 1) ? s0B[8 + e] : s0B[e]);
        pkA[e] = f2bf(__builtin_amdgcn_exp2f(svA));
        pkB[e] = f2bf(__builtin_amdgcn_exp2f(svB));
      }
      bf16x8 paA = __builtin_bit_cast(bf16x8, pkA);
      bf16x8 paB = __builtin_bit_cast(bf16x8, pkB);

      bf16x8 vf0 = *(const bf16x8*)&Vp[(size_t)l31 * SEQ + (2 * t + hi) * 8];
      bf16x8 vf1 = *(const bf16x8*)&Vp[(size_t)(32 + l31) * SEQ + (2 * t + hi) * 8];
      lA   = __builtin_amdgcn_mfma_f32_32x32x16_bf16(paA, ones, lA, 0, 0, 0);
      oa0A = __builtin_amdgcn_mfma_f32_32x32x16_bf16(paA, vf0, oa0A, 0, 0, 0);
      oa1A = __builtin_amdgcn_mfma_f32_32x32x16_bf16(paA, vf1, oa1A, 0, 0, 0);
      lB   = __builtin_amdgcn_mfma_f32_32x32x16_bf16(paB, ones, lB, 0, 0, 0);
      oa0B = __builtin_amdgcn_mfma_f32_32x32x16_bf16(paB, vf0, oa0B, 0, 0, 0);
      oa1B = __builtin_amdgcn_mfma_f32_32x32x16_bf16(paB, vf1, oa1B, 0, 0, 0);
    }
  }

  // ---- split-K combine (exact: constant m, partials add), 2 phases ----
  int b = bh >> 4, hh = bh & 15;

  // phase A
  if (h == 1) {
#pragma unroll
    for (int r = 0; r < 16; ++r) {
      cf[s * 3072 + r * 64 + lane]        = oa0A[r];
      cf[s * 3072 + 1024 + r * 64 + lane] = oa1A[r];
      cf[s * 3072 + 2048 + r * 64 + lane] = lA[r];
    }
  }
  __syncthreads();
  if (h == 0) {
#pragma unroll
    for (int reg = 0; reg < 16; ++reg) {
      float o0 = oa0A[reg] + cf[s * 3072 + reg * 64 + lane];
      float o1 = oa1A[reg] + cf[s * 3072 + 1024 + reg * 64 + lane];
      float lv = lA[reg]   + cf[s * 3072 + 2048 + reg * 64 + lane];
      float inv = 1.0f / lv;
      int q = qA + (reg & 3) + 8 * (reg >> 2) + 4 * hi;
      size_t rowoff = ((size_t)(b * SEQ + q)) * DMODEL + hh * HD;
      Oa[rowoff + l31]      = f2bf(o0 * inv);
      Oa[rowoff + 32 + l31] = f2bf(o1 * inv);
    }
  }
  __syncthreads();
  // phase B
  if (h == 1) {
#pragma unroll
    for (int r = 0; r < 16; ++r) {
      cf[s * 3072 + r * 64 + lane]        = oa0B[r];
      cf[s * 3072 + 1024 + r * 64 + lane] = oa1B[r];
      cf[s * 3072 + 2048 + r * 64 + lane] = lB[r];
    }
  }
  __syncthreads();
  if (h == 0) {
#pragma unroll
    for (int reg = 0; reg < 16; ++reg) {
      float o0 = oa0B[reg] + cf[s * 3072 + reg * 64 + lane];
      float o1 = oa1B[reg] + cf[s * 3072 + 1024 + reg * 64 + lane];
      float lv = lB[reg]   + cf[s * 3072 + 2048 + reg * 64 + lane];
      float inv = 1.0f / lv;
      int q = qA + 32 + (reg & 3) + 8 * (reg >> 2) + 4 * hi;
      size_t rowoff = ((size_t)(b * SEQ + q)) * DMODEL + hh * HD;
      Oa[rowoff + l31]      = f2bf(o0 * inv);
      Oa[rowoff + 32 + l31] = f2bf(o1 * inv);
    }
  }
}

extern "C" void kernel_launch(void* const* d_in, const int* in_sizes, int n_in,
                              void* d_out, int out_size, void* d_ws, size_t ws_size,
                              hipStream_t stream) {
  const float* x  = (const float*)d_in[0];
  const float* Wq = (const float*)d_in[1];
  const float* bq = (const float*)d_in[2];
  const float* Wk = (const float*)d_in[3];
  const float* bk = (const float*)d_in[4];
  const float* Wv = (const float*)d_in[5];
  const float* bv = (const float*)d_in[6];
  const float* Wo = (const float*)d_in[7];
  const float* bo = (const float*)d_in[8];

  char* ws = (char*)d_ws;
  const size_t MB = 1024 * 1024;
  u16* xb    = (u16*)(ws);            // 8 MB  x bf16 [4096,1024]
  u16* wqT   = (u16*)(ws + 8 * MB);   // 2 MB each, W^T bf16
  u16* wkT   = (u16*)(ws + 10 * MB);
  u16* wvT   = (u16*)(ws + 12 * MB);
  u16* woT   = (u16*)(ws + 14 * MB);
  u16* qbuf  = (u16*)(ws + 16 * MB);  // 8 MB [bh][n][hd] (pre-scaled)
  u16* kbuf  = (u16*)(ws + 24 * MB);  // 8 MB [bh][n][hd]
  u16* vbufT = (u16*)(ws + 32 * MB);  // 8 MB [bh][hd][n'] (k-permuted)
  u16* abuf  = (u16*)(ws + 40 * MB);  // 8 MB attn out bf16 [4096,1024]

  k_cvt<<<2048, 256, 0, stream>>>(x, xb, (MTOT * DMODEL) / 8);
  k_cvtT<<<dim3(16, 16, 4), 256, 0, stream>>>(Wq, Wk, Wv, Wo, wqT, wkT, wvT, woT);
  k_gemm<0><<<dim3(DMODEL / 128, MTOT / 128, 3), 256, 0, stream>>>(
      xb, wqT, wkT, wvT, bq, bk, bv, qbuf, kbuf, vbufT, MTOT, DMODEL, DMODEL);
  k_attn<<<dim3(SEQ / 128, BATCH * HEADS), 256, 0, stream>>>(qbuf, kbuf, vbufT, abuf);
  k_gemm<1><<<dim3(DMODEL / 128, MTOT / 128, 1), 256, 0, stream>>>(
      abuf, woT, woT, woT, bo, bo, bo, d_out, d_out, d_out, MTOT, DMODEL, DMODEL);
}

// Round 15
// 105.902 us; speedup vs baseline: 1.2930x; 1.2930x over previous
//
#include <hip/hip_runtime.h>

#define HEADS 16
#define HD 64
#define SEQ 2048
#define DMODEL 1024
#define BATCH 2
#define MTOT (BATCH*SEQ)   // 4096
#define KVB 64
#define NKH 16             // k-tiles per half (split-k=2)

typedef unsigned short u16;
typedef __bf16 bf16;
typedef bf16 bf16x8 __attribute__((ext_vector_type(8)));
typedef float f32x4 __attribute__((ext_vector_type(4)));
typedef float f32x16 __attribute__((ext_vector_type(16)));
typedef unsigned short u16x8 __attribute__((ext_vector_type(8)));
typedef unsigned short u16x4 __attribute__((ext_vector_type(4)));

static __device__ __forceinline__ u16 f2bf(float f) {
  bf16 b = (bf16)f;
  return __builtin_bit_cast(u16, b);
}

// async global->LDS, 16B per lane. LDS dest is wave-uniform base; HW scatters
// lane i at base + 16*i. Global src is per-lane (enables source pre-swizzle).
static __device__ __forceinline__ void async16(u16* lds_base, const u16* g) {
  __builtin_amdgcn_global_load_lds(
      (const __attribute__((address_space(1))) unsigned int*)g,
      (__attribute__((address_space(3))) unsigned int*)lds_base,
      16, 0, 0);
}

// ---------------- convert x: f32 -> bf16, 8 elems/thread ----------------
__global__ __launch_bounds__(256) void k_cvt(const float* __restrict__ in,
                                             u16* __restrict__ out, int n8) {
  int i = blockIdx.x * blockDim.x + threadIdx.x;
  if (i >= n8) return;
  const float4* p = (const float4*)(in + (size_t)i * 8);
  float4 a = p[0], b = p[1];
  u16x8 r;
  r[0] = f2bf(a.x); r[1] = f2bf(a.y); r[2] = f2bf(a.z); r[3] = f2bf(a.w);
  r[4] = f2bf(b.x); r[5] = f2bf(b.y); r[6] = f2bf(b.z); r[7] = f2bf(b.w);
  *(u16x8*)(out + (size_t)i * 8) = r;
}

// ------------- convert + transpose W: f32 [K,N] -> bf16 [N,K] -------------
__global__ __launch_bounds__(256) void k_cvtT(const float* __restrict__ W0, const float* __restrict__ W1,
                                              const float* __restrict__ W2, const float* __restrict__ W3,
                                              u16* __restrict__ T0, u16* __restrict__ T1,
                                              u16* __restrict__ T2, u16* __restrict__ T3) {
  const float* W = blockIdx.z == 0 ? W0 : blockIdx.z == 1 ? W1 : blockIdx.z == 2 ? W2 : W3;
  u16*         T = blockIdx.z == 0 ? T0 : blockIdx.z == 1 ? T1 : blockIdx.z == 2 ? T2 : T3;
  __shared__ u16 tile[64 * 68];
  int t = threadIdx.x;
  int kb = blockIdx.y * 64, nb = blockIdx.x * 64;
#pragma unroll
  for (int i = 0; i < 4; ++i) {
    int c = t * 4 + i;
    int row = c >> 4;
    int c4 = c & 15;
    float4 v = *(const float4*)&W[(size_t)(kb + row) * DMODEL + nb + c4 * 4];
    tile[row * 68 + c4 * 4 + 0] = f2bf(v.x);
    tile[row * 68 + c4 * 4 + 1] = f2bf(v.y);
    tile[row * 68 + c4 * 4 + 2] = f2bf(v.z);
    tile[row * 68 + c4 * 4 + 3] = f2bf(v.w);
  }
  __syncthreads();
#pragma unroll
  for (int i = 0; i < 2; ++i) {
    int c = t * 2 + i;
    int n = c >> 3;
    int k8 = c & 7;
    u16x8 v;
#pragma unroll
    for (int e = 0; e < 8; ++e) v[e] = tile[(k8 * 8 + e) * 68 + n];
    *(u16x8*)&T[(size_t)(nb + n) * DMODEL + kb + k8 * 8] = v;
  }
}

// -------- GEMM (QKV): C[M,N] = A[M,K] @ BT[N,K]^T + bias --------
// 2-phase double-buffered pipeline (one raw s_barrier + own-wave vmcnt(0)
// per K-step). z=0 -> Q*(scale*log2e) head-split [bh][n][hd]; z=1 -> K
// head-split; z=2 -> V^T [bh][hd][n'] with n' = per-16-group k-permutation
// (swap bits 2<->3 of n&15) matching the attn C/D-reg score order.
__global__ __launch_bounds__(256) void k_gemm(
    const u16* __restrict__ A,
    const u16* __restrict__ BT0, const u16* __restrict__ BT1, const u16* __restrict__ BT2,
    const float* __restrict__ b0, const float* __restrict__ b1, const float* __restrict__ b2,
    void* __restrict__ O0, void* __restrict__ O1, void* __restrict__ O2,
    int M, int N, int K) {
  const u16* BT = blockIdx.z == 0 ? BT0 : blockIdx.z == 1 ? BT1 : BT2;
  const float* bias = blockIdx.z == 0 ? b0 : blockIdx.z == 1 ? b1 : b2;
  void* Out = blockIdx.z == 0 ? O0 : blockIdx.z == 1 ? O1 : O2;

  __shared__ u16 Ads[2][128 * 32];  // 16KB
  __shared__ u16 Bds[2][128 * 32];  // 16KB
  int tid = threadIdx.x, wid = tid >> 6, lane = tid & 63;
  int r = lane & 15, g = lane >> 4;
  int wm = wid >> 1, wn = wid & 1;
  int m0 = blockIdx.y * 128, n0 = blockIdx.x * 128;

  f32x4 acc[4][4];
  f32x4 zero4 = {0.f, 0.f, 0.f, 0.f};
#pragma unroll
  for (int mt = 0; mt < 4; ++mt)
#pragma unroll
    for (int nt = 0; nt < 4; ++nt) acc[mt][nt] = zero4;

  int srow = lane >> 2;
  int scb = lane & 3;

  auto STAGE = [&](int b, int k0) {
#pragma unroll
    for (int tt = 0; tt < 2; ++tt) {
      int inst = wid * 2 + tt;
      int row = inst * 16 + srow;
      async16(&Ads[b][inst * 512], &A[(size_t)(m0 + row) * K + k0 + scb * 8]);
      async16(&Bds[b][inst * 512], &BT[(size_t)(n0 + row) * K + k0 + scb * 8]);
    }
  };

  auto BODY = [&](int buf, int k0) {
    if (k0 + 32 < K) STAGE(buf ^ 1, k0 + 32);  // flies under this step's MFMA
    bf16x8 af[4], bfv[4];
#pragma unroll
    for (int mt = 0; mt < 4; ++mt)
      af[mt] = *(const bf16x8*)&Ads[buf][(wm * 64 + mt * 16 + r) * 32 + g * 8];
#pragma unroll
    for (int nt = 0; nt < 4; ++nt)
      bfv[nt] = *(const bf16x8*)&Bds[buf][(wn * 64 + nt * 16 + r) * 32 + g * 8];
#pragma unroll
    for (int mt = 0; mt < 4; ++mt)
#pragma unroll
      for (int nt = 0; nt < 4; ++nt)
        acc[mt][nt] = __builtin_amdgcn_mfma_f32_16x16x32_bf16(af[mt], bfv[nt], acc[mt][nt], 0, 0, 0);
    asm volatile("s_waitcnt vmcnt(0)" ::: "memory");
    __builtin_amdgcn_sched_barrier(0);
    __builtin_amdgcn_s_barrier();
    __builtin_amdgcn_sched_barrier(0);
  };

  STAGE(0, 0);
  asm volatile("s_waitcnt vmcnt(0)" ::: "memory");
  __builtin_amdgcn_sched_barrier(0);
  __builtin_amdgcn_s_barrier();
  __builtin_amdgcn_sched_barrier(0);

  for (int k0 = 0; k0 < K; k0 += 64) {  // K % 64 == 0
    BODY(0, k0);
    BODY(1, k0 + 32);
  }

  const float qs = 0.18033688011112042f;  // hd^-0.5 * log2(e)
#pragma unroll
  for (int nt = 0; nt < 4; ++nt) {
    int col = n0 + wn * 64 + nt * 16 + r;
    float bv = bias[col];
#pragma unroll
    for (int mt = 0; mt < 4; ++mt) {
      int rowb = m0 + wm * 64 + mt * 16 + g * 4;
      int b = rowb >> 11;
      int h = col >> 6, d = col & (HD - 1);
      if (blockIdx.z == 2) {
        int n = rowb & (SEQ - 1);
        int np = (n & ~12) | ((n & 4) << 1) | ((n & 8) >> 1);
        u16x4 pk;
#pragma unroll
        for (int j = 0; j < 4; ++j) pk[j] = f2bf(acc[mt][nt][j] + bv);
        *(u16x4*)&((u16*)Out)[((size_t)((b * HEADS + h) * HD + d)) * SEQ + np] = pk;
      } else {
        float sc = (blockIdx.z == 0) ? qs : 1.0f;
#pragma unroll
        for (int j = 0; j < 4; ++j) {
          int row = rowb + j;
          int n = row & (SEQ - 1);
          ((u16*)Out)[((size_t)(b * HEADS + h) * SEQ + n) * HD + d] = f2bf((acc[mt][nt][j] + bv) * sc);
        }
      }
    }
  }
}

// -------- output GEMM: in-block split-K x2, 8 waves, f32 out --------
// gemm1 was the weak dispatch: 256 blocks x 4 waves = 1 block/CU, K=1024
// serial. Here waves = (h = K-half, w = output quadrant); each half runs an
// independent 2-phase pipeline over 512 of K (16 bodies), halves combined by
// exact f32 ADD through the (aliased) staging LDS. 64KB LDS -> 2 blocks/CU
// co-resident (16 waves/CU): one block's barrier stall fills with the other's
// compute — the proven attn-R8 pattern applied to the GEMM.
__global__ __launch_bounds__(512, 2) void k_gemm1(
    const u16* __restrict__ A, const u16* __restrict__ BT,
    const float* __restrict__ bias, float* __restrict__ Out,
    int M, int N, int K) {
  __shared__ u16 smem[32768];  // 64KB: A[b][h] 4x8KB | B[b][h] 4x8KB; combine aliases
  u16* Apart = smem;
  u16* Bpart = smem + 16384;

  int tid = threadIdx.x, wid = tid >> 6, lane = tid & 63;
  int r = lane & 15, g = lane >> 4;
  int h = wid >> 2, w = wid & 3;
  int wm = w >> 1, wn = w & 1;

  // bijective XCD swizzle (256 blocks % 8 == 0): each XCD owns 4 M-panels
  int fid = blockIdx.y * gridDim.x + blockIdx.x;  // gridDim = (8, 32)
  int nb = (fid & 7) * 32 + (fid >> 3);
  int m0 = (nb >> 3) * 128, n0 = (nb & 7) * 128;

  f32x4 acc[4][4];
  f32x4 zero4 = {0.f, 0.f, 0.f, 0.f};
#pragma unroll
  for (int mt = 0; mt < 4; ++mt)
#pragma unroll
    for (int nt = 0; nt < 4; ++nt) acc[mt][nt] = zero4;

  int srow = lane >> 2;
  int scb = lane & 3;
  const int KH = K >> 1;  // 512

  auto STAGE = [&](int b, int k0) {  // k0 local to this wave's half
    int kg = h * KH + k0;
#pragma unroll
    for (int tt = 0; tt < 2; ++tt) {
      int inst = w * 2 + tt;            // 0..7 within the half's 4 waves
      int row = inst * 16 + srow;
      async16(&Apart[((b * 2 + h) * 8 + inst) * 512], &A[(size_t)(m0 + row) * K + kg + scb * 8]);
      async16(&Bpart[((b * 2 + h) * 8 + inst) * 512], &BT[(size_t)(n0 + row) * K + kg + scb * 8]);
    }
  };

  auto BODY = [&](int buf, int k0) {
    if (k0 + 32 < KH) STAGE(buf ^ 1, k0 + 32);
    const u16* Ab = &Apart[(buf * 2 + h) * 4096];
    const u16* Bb = &Bpart[(buf * 2 + h) * 4096];
    bf16x8 af[4], bfv[4];
#pragma unroll
    for (int mt = 0; mt < 4; ++mt)
      af[mt] = *(const bf16x8*)&Ab[(wm * 64 + mt * 16 + r) * 32 + g * 8];
#pragma unroll
    for (int nt = 0; nt < 4; ++nt)
      bfv[nt] = *(const bf16x8*)&Bb[(wn * 64 + nt * 16 + r) * 32 + g * 8];
#pragma unroll
    for (int mt = 0; mt < 4; ++mt)
#pragma unroll
      for (int nt = 0; nt < 4; ++nt)
        acc[mt][nt] = __builtin_amdgcn_mfma_f32_16x16x32_bf16(af[mt], bfv[nt], acc[mt][nt], 0, 0, 0);
    asm volatile("s_waitcnt vmcnt(0)" ::: "memory");
    __builtin_amdgcn_sched_barrier(0);
    __builtin_amdgcn_s_barrier();
    __builtin_amdgcn_sched_barrier(0);
  };

  STAGE(0, 0);
  asm volatile("s_waitcnt vmcnt(0)" ::: "memory");
  __builtin_amdgcn_sched_barrier(0);
  __builtin_amdgcn_s_barrier();
  __builtin_amdgcn_sched_barrier(0);

  for (int k0 = 0; k0 < KH; k0 += 64) {  // 8 iters, 16 bodies
    BODY(0, k0);
    BODY(1, k0 + 32);
  }

  // ---- split-K combine (exact f32 add) through aliased staging LDS ----
  __syncthreads();
  float* cfp = (float*)smem;  // [128][128] f32 = 64KB
  if (h == 1) {
#pragma unroll
    for (int mt = 0; mt < 4; ++mt)
#pragma unroll
      for (int nt = 0; nt < 4; ++nt)
#pragma unroll
        for (int j = 0; j < 4; ++j)
          cfp[(wm * 64 + mt * 16 + g * 4 + j) * 128 + wn * 64 + nt * 16 + r] = acc[mt][nt][j];
  }
  __syncthreads();
  if (h == 0) {
#pragma unroll
    for (int nt = 0; nt < 4; ++nt) {
      int col = n0 + wn * 64 + nt * 16 + r;
      float bv = bias[col];
#pragma unroll
      for (int mt = 0; mt < 4; ++mt) {
        int rowb = m0 + wm * 64 + mt * 16 + g * 4;
#pragma unroll
        for (int j = 0; j < 4; ++j) {
          float v = acc[mt][nt][j] + bv +
                    cfp[(wm * 64 + mt * 16 + g * 4 + j) * 128 + wn * 64 + nt * 16 + r];
          Out[(size_t)(rowb + j) * N + col] = v;
        }
      }
    }
  }
}

// -------- flash attention: split-K x2, 2 q-subtiles/wave (R10-verbatim) --------
// Block = (bh, 256 q-rows), 8 waves (512 thr). Wave w: q-pair s=w&3 (64 rows,
// two 32-row subtiles A/B), k-half h=w>>2 (1024 keys, 16 tiles of 64).
// Each K/V fragment read from LDS feeds BOTH subtiles (halves LDS read
// traffic per q). Swapped QK^T on 32x32x16 MFMA: lane owns one q-row's
// scores; softmax = exp2 only (scores provably bounded, softmax
// shift-invariance -> m==0 exact). Split-K partials combine by exact ADD
// through LDS in two phases (A then B). Best-measured attn: 42.6us (R10).
__global__ __launch_bounds__(512, 2) void k_attn(const u16* __restrict__ Q,
                                                 const u16* __restrict__ Kg,
                                                 const u16* __restrict__ Vt,
                                                 u16* __restrict__ Oa) {
  __shared__ u16 lds[2][2][2][KVB * 64];  // [dbuf][half][K|V][4096] = 64KB

  int tid = threadIdx.x, wid = tid >> 6, lane = tid & 63;
  int l31 = lane & 31, hi = lane >> 5;
  int h = wid >> 2, s = wid & 3;

  // XCD-aware swizzle: 256 blocks, 8 XCDs -> 4 heads per XCD (K/V L2-resident)
  int fid = blockIdx.y * gridDim.x + blockIdx.x;  // gridDim = (8, 32)
  int swz = (fid & 7) * 32 + (fid >> 3);
  int qt = swz & 7;
  int bh = swz >> 3;

  const size_t kbase = (size_t)bh * SEQ * HD;  // Q,K: [bh][n][64]
  const size_t vbase = (size_t)bh * HD * SEQ;  // Vt:  [bh][64][2048']
  int qA = qt * 256 + s * 64;  // subtile A rows; B = +32

  bf16x8 qfA[4], qfB[4];
#pragma unroll
  for (int db = 0; db < 4; ++db) {
    qfA[db] = *(const bf16x8*)&Q[kbase + (size_t)(qA + l31) * HD + db * 16 + hi * 8];
    qfB[db] = *(const bf16x8*)&Q[kbase + (size_t)(qA + 32 + l31) * HD + db * 16 + hi * 8];
  }

  int swz7 = l31 & 7;
  int coff[4];
#pragma unroll
  for (int i = 0; i < 4; ++i) coff[i] = ((2 * i + hi) ^ swz7) * 8;

  f32x16 zero16 = {0.f,0.f,0.f,0.f,0.f,0.f,0.f,0.f,0.f,0.f,0.f,0.f,0.f,0.f,0.f,0.f};
  f32x16 oa0A = zero16, oa1A = zero16, lA = zero16;
  f32x16 oa0B = zero16, oa1B = zero16, lB = zero16;

  u16x8 onesb;
#pragma unroll
  for (int e = 0; e < 8; ++e) onesb[e] = 0x3F80;  // bf16 1.0
  bf16x8 ones = __builtin_bit_cast(bf16x8, onesb);

  auto STAGE = [&](int b, int kc) {  // kc local to this wave's half
    int kof = (h * NKH + kc) * KVB;
#pragma unroll
    for (int i = 0; i < 2; ++i) {
      int inst = s * 2 + i;             // 0..7 within the half's 4 waves
      int rr = inst * 8 + (lane >> 3);  // row 0..63
      int ch = (lane & 7) ^ (rr & 7);
      async16(&lds[b][h][0][inst * 512], &Kg[kbase + (size_t)(kof + rr) * HD + ch * 8]);
      async16(&lds[b][h][1][inst * 512], &Vt[vbase + (size_t)rr * SEQ + kof + ch * 8]);
    }
  };

  auto BODY = [&](int buf, int kc) {
    if (kc + 1 < NKH) STAGE(buf ^ 1, kc + 1);  // flies under this iter's compute

    const u16* Kb = &lds[buf][h][0][0];
    const u16* Vb = &lds[buf][h][1][0];

    f32x16 s0A = zero16, s1A = zero16, s0B = zero16, s1B = zero16;
#pragma unroll
    for (int db = 0; db < 4; ++db) {
      bf16x8 kf0 = *(const bf16x8*)&Kb[l31 * 64 + coff[db]];
      bf16x8 kf1 = *(const bf16x8*)&Kb[2048 + l31 * 64 + coff[db]];
      s0A = __builtin_amdgcn_mfma_f32_32x32x16_bf16(kf0, qfA[db], s0A, 0, 0, 0);
      s1A = __builtin_amdgcn_mfma_f32_32x32x16_bf16(kf1, qfA[db], s1A, 0, 0, 0);
      s0B = __builtin_amdgcn_mfma_f32_32x32x16_bf16(kf0, qfB[db], s0B, 0, 0, 0);
      s1B = __builtin_amdgcn_mfma_f32_32x32x16_bf16(kf1, qfB[db], s1B, 0, 0, 0);
    }

#pragma unroll
    for (int t = 0; t < 4; ++t) {
      u16x8 pkA, pkB;
#pragma unroll
      for (int e = 0; e < 8; ++e) {
        float svA = (t & 2) ? ((t & 1) ? s1A[8 + e] : s1A[e])
                            : ((t & 1) ? s0A[8 + e] : s0A[e]);
        float svB = (t & 2) ? ((t & 1) ? s1B[8 + e] : s1B[e])
                            : ((t & 1) ? s0B[8 + e] : s0B[e]);
        pkA[e] = f2bf(__builtin_amdgcn_exp2f(svA));
        pkB[e] = f2bf(__builtin_amdgcn_exp2f(svB));
      }
      bf16x8 paA = __builtin_bit_cast(bf16x8, pkA);
      bf16x8 paB = __builtin_bit_cast(bf16x8, pkB);

      bf16x8 vf0 = *(const bf16x8*)&Vb[l31 * 64 + coff[t]];
      bf16x8 vf1 = *(const bf16x8*)&Vb[2048 + l31 * 64 + coff[t]];
      lA   = __builtin_amdgcn_mfma_f32_32x32x16_bf16(paA, ones, lA, 0, 0, 0);
      oa0A = __builtin_amdgcn_mfma_f32_32x32x16_bf16(paA, vf0, oa0A, 0, 0, 0);
      oa1A = __builtin_amdgcn_mfma_f32_32x32x16_bf16(paA, vf1, oa1A, 0, 0, 0);
      lB   = __builtin_amdgcn_mfma_f32_32x32x16_bf16(paB, ones, lB, 0, 0, 0);
      oa0B = __builtin_amdgcn_mfma_f32_32x32x16_bf16(paB, vf0, oa0B, 0, 0, 0);
      oa1B = __builtin_amdgcn_mfma_f32_32x32x16_bf16(paB, vf1, oa1B, 0, 0, 0);
    }

    asm volatile("s_waitcnt vmcnt(0)" ::: "memory");
    __builtin_amdgcn_sched_barrier(0);
    __builtin_amdgcn_s_barrier();
    __builtin_amdgcn_sched_barrier(0);
  };

  STAGE(0, 0);
  asm volatile("s_waitcnt vmcnt(0)" ::: "memory");
  __builtin_amdgcn_sched_barrier(0);
  __builtin_amdgcn_s_barrier();
  __builtin_amdgcn_sched_barrier(0);

  for (int kc = 0; kc < NKH; kc += 2) {
    BODY(0, kc);
    BODY(1, kc + 1);
  }

  // ---- split-K combine (exact: constant m, partials add), 2 phases ----
  float* cf = (float*)&lds[0][0][0][0];
  int b = bh >> 4, hh = bh & 15;

  // phase A
  if (h == 1) {
#pragma unroll
    for (int r2 = 0; r2 < 16; ++r2) {
      cf[s * 3072 + r2 * 64 + lane]        = oa0A[r2];
      cf[s * 3072 + 1024 + r2 * 64 + lane] = oa1A[r2];
      cf[s * 3072 + 2048 + r2 * 64 + lane] = lA[r2];
    }
  }
  __syncthreads();
  if (h == 0) {
#pragma unroll
    for (int reg = 0; reg < 16; ++reg) {
      float o0 = oa0A[reg] + cf[s * 3072 + reg * 64 + lane];
      float o1 = oa1A[reg] + cf[s * 3072 + 1024 + reg * 64 + lane];
      float lv = lA[reg]   + cf[s * 3072 + 2048 + reg * 64 + lane];
      float inv = 1.0f / lv;
      int q = qA + (reg & 3) + 8 * (reg >> 2) + 4 * hi;
      size_t rowoff = ((size_t)(b * SEQ + q)) * DMODEL + hh * HD;
      Oa[rowoff + l31]      = f2bf(o0 * inv);
      Oa[rowoff + 32 + l31] = f2bf(o1 * inv);
    }
  }
  __syncthreads();
  // phase B
  if (h == 1) {
#pragma unroll
    for (int r2 = 0; r2 < 16; ++r2) {
      cf[s * 3072 + r2 * 64 + lane]        = oa0B[r2];
      cf[s * 3072 + 1024 + r2 * 64 + lane] = oa1B[r2];
      cf[s * 3072 + 2048 + r2 * 64 + lane] = lB[r2];
    }
  }
  __syncthreads();
  if (h == 0) {
#pragma unroll
    for (int reg = 0; reg < 16; ++reg) {
      float o0 = oa0B[reg] + cf[s * 3072 + reg * 64 + lane];
      float o1 = oa1B[reg] + cf[s * 3072 + 1024 + reg * 64 + lane];
      float lv = lB[reg]   + cf[s * 3072 + 2048 + reg * 64 + lane];
      float inv = 1.0f / lv;
      int q = qA + 32 + (reg & 3) + 8 * (reg >> 2) + 4 * hi;
      size_t rowoff = ((size_t)(b * SEQ + q)) * DMODEL + hh * HD;
      Oa[rowoff + l31]      = f2bf(o0 * inv);
      Oa[rowoff + 32 + l31] = f2bf(o1 * inv);
    }
  }
}

extern "C" void kernel_launch(void* const* d_in, const int* in_sizes, int n_in,
                              void* d_out, int out_size, void* d_ws, size_t ws_size,
                              hipStream_t stream) {
  const float* x  = (const float*)d_in[0];
  const float* Wq = (const float*)d_in[1];
  const float* bq = (const float*)d_in[2];
  const float* Wk = (const float*)d_in[3];
  const float* bk = (const float*)d_in[4];
  const float* Wv = (const float*)d_in[5];
  const float* bv = (const float*)d_in[6];
  const float* Wo = (const float*)d_in[7];
  const float* bo = (const float*)d_in[8];

  char* ws = (char*)d_ws;
  const size_t MB = 1024 * 1024;
  u16* xb    = (u16*)(ws);            // 8 MB  x bf16 [4096,1024]
  u16* wqT   = (u16*)(ws + 8 * MB);   // 2 MB each, W^T bf16
  u16* wkT   = (u16*)(ws + 10 * MB);
  u16* wvT   = (u16*)(ws + 12 * MB);
  u16* woT   = (u16*)(ws + 14 * MB);
  u16* qbuf  = (u16*)(ws + 16 * MB);  // 8 MB [bh][n][hd] (pre-scaled)
  u16* kbuf  = (u16*)(ws + 24 * MB);  // 8 MB [bh][n][hd]
  u16* vbufT = (u16*)(ws + 32 * MB);  // 8 MB [bh][hd][n'] (k-permuted)
  u16* abuf  = (u16*)(ws + 40 * MB);  // 8 MB attn out bf16 [4096,1024]

  k_cvt<<<2048, 256, 0, stream>>>(x, xb, (MTOT * DMODEL) / 8);
  k_cvtT<<<dim3(16, 16, 4), 256, 0, stream>>>(Wq, Wk, Wv, Wo, wqT, wkT, wvT, woT);
  k_gemm<<<dim3(DMODEL / 128, MTOT / 128, 3), 256, 0, stream>>>(
      xb, wqT, wkT, wvT, bq, bk, bv, qbuf, kbuf, vbufT, MTOT, DMODEL, DMODEL);
  k_attn<<<dim3(SEQ / 256, BATCH * HEADS), 512, 0, stream>>>(qbuf, kbuf, vbufT, abuf);
  k_gemm1<<<dim3(DMODEL / 128, MTOT / 128), 512, 0, stream>>>(
      abuf, woT, bo, (float*)d_out, MTOT, DMODEL, DMODEL);
}